// Round 4
// baseline (112.045 us; speedup 1.0000x reference)
//
#include <hip/hip_runtime.h>

// RankingLoss via target-rank sort:
//   loss = (1/N) * sum_i [ cnt_i>0 ? (sum_{j: t[j]<t[i]} max(0, m - p[i] + p[j])) / cnt_i : 0 ]
// Key: in target-sorted order the mask set for row i is exactly the slot
// prefix [0, strict_rank_i), and cnt_i = strict_rank_i. So:
//   Pass 1: compute strict ranks (ballot-count, 1 v_cmp/pair), scatter pred
//           into sorted slots (ties resolved by atomic counter — set-invariant).
//   Pass 2: per block of 8 consecutive slots, hot loop over the common prefix
//           is compare-free: sum += max(0, c_r + p_sorted[j])  (3 VALU/pair,
//           N^2/2 total pairs). Tiny predicated tail covers K-spread from ties.

constexpr float MARGIN = 0.1f;
constexpr int T   = 256;   // threads per block
constexpr int R1  = 16;    // rows per block, pass 1
constexpr int R2  = 8;     // slots per block, pass 2

__global__ __launch_bounds__(T) void rank_scatter(const float* __restrict__ pred,
                                                  const float* __restrict__ target,
                                                  float* __restrict__ p_sorted,
                                                  int* __restrict__ K_sorted,
                                                  unsigned int* __restrict__ tie_ctr,
                                                  int n) {
    const int base = blockIdx.x * R1;

    float ti[R1];
    #pragma unroll
    for (int r = 0; r < R1; ++r) ti[r] = target[base + r];

    unsigned int cnt[R1];   // wave-uniform (ballot-counted)
    #pragma unroll
    for (int r = 0; r < R1; ++r) cnt[r] = 0u;

    const float4* __restrict__ t4 = (const float4*)target;
    const int n4 = n >> 2;   // 4096, exact multiple of T: no partial waves

    for (int j = (int)threadIdx.x; j < n4; j += T) {
        const float4 tj = t4[j];
        #pragma unroll
        for (int r = 0; r < R1; ++r) {
            const float tir = ti[r];
            cnt[r] += (unsigned)__popcll(__ballot(tj.x < tir));
            cnt[r] += (unsigned)__popcll(__ballot(tj.y < tir));
            cnt[r] += (unsigned)__popcll(__ballot(tj.z < tir));
            cnt[r] += (unsigned)__popcll(__ballot(tj.w < tir));
        }
    }

    __shared__ unsigned int lc[T / 64][R1];
    const int lane = threadIdx.x & 63;
    const int wv   = threadIdx.x >> 6;
    if (lane == 0) {
        #pragma unroll
        for (int r = 0; r < R1; ++r) lc[wv][r] = cnt[r];
    }
    __syncthreads();

    if ((int)threadIdx.x < R1) {
        const int r = threadIdx.x;
        const unsigned int strict = lc[0][r] + lc[1][r] + lc[2][r] + lc[3][r];
        // Unique slot within the tie group (any internal order is correct:
        // pass 2 only ever sums over the full prefix set).
        const int slot = (int)strict + (int)atomicAdd(&tie_ctr[strict], 1u);
        p_sorted[slot] = pred[base + r];
        K_sorted[slot] = (int)strict;
    }
}

__global__ __launch_bounds__(T) void hinge_sorted(const float* __restrict__ p_sorted,
                                                  const int* __restrict__ K_sorted,
                                                  float* __restrict__ out,
                                                  int n, float inv_n) {
    const int base = blockIdx.x * R2;

    float c[R2];
    int   K[R2];   // monotone non-decreasing in slot; K[r] <= base+r
    #pragma unroll
    for (int r = 0; r < R2; ++r) {
        K[r] = K_sorted[base + r];
        c[r] = MARGIN - p_sorted[base + r];
    }
    const int Kmin = K[0];
    const int Kmax = K[R2 - 1];

    float sum[R2];
    #pragma unroll
    for (int r = 0; r < R2; ++r) sum[r] = 0.f;

    // Main loop: compare-free over the common prefix [0, 4*(Kmin/4)).
    const float4* __restrict__ p4 = (const float4*)p_sorted;
    const int n4m = Kmin >> 2;
    for (int j = (int)threadIdx.x; j < n4m; j += T) {
        const float4 p = p4[j];
        #pragma unroll
        for (int r = 0; r < R2; ++r) {
            const float cr = c[r];
            sum[r] += fmaxf(0.f, cr + p.x);
            sum[r] += fmaxf(0.f, cr + p.y);
            sum[r] += fmaxf(0.f, cr + p.z);
            sum[r] += fmaxf(0.f, cr + p.w);
        }
    }

    // Predicated tail: j in [4*(Kmin/4), Kmax). For tie-free data this is
    // <= ~11 elements; stays correct (just slower) for heavy ties.
    for (int j = (n4m << 2) + (int)threadIdx.x; j < Kmax; j += T) {
        const float pj = p_sorted[j];
        #pragma unroll
        for (int r = 0; r < R2; ++r) {
            sum[r] += (j < K[r]) ? fmaxf(0.f, c[r] + pj) : 0.f;
        }
    }

    // Reduce sums across the block.
    __shared__ float ls[T / 64][R2];
    __shared__ float row_val[R2];
    const int lane = threadIdx.x & 63;
    const int wv   = threadIdx.x >> 6;

    #pragma unroll
    for (int r = 0; r < R2; ++r) {
        float s = sum[r];
        #pragma unroll
        for (int off = 32; off > 0; off >>= 1) s += __shfl_down(s, off, 64);
        if (lane == 0) ls[wv][r] = s;
    }
    __syncthreads();

    if ((int)threadIdx.x < R2) {
        const int r = threadIdx.x;
        const float s = ls[0][r] + ls[1][r] + ls[2][r] + ls[3][r];
        row_val[r] = (K[r] > 0) ? (s / (float)K[r]) : 0.f;
    }
    __syncthreads();

    if (threadIdx.x == 0) {
        float local = 0.f;
        #pragma unroll
        for (int r = 0; r < R2; ++r) local += row_val[r];
        atomicAdd(out, local * inv_n);
    }
}

extern "C" void kernel_launch(void* const* d_in, const int* in_sizes, int n_in,
                              void* d_out, int out_size, void* d_ws, size_t ws_size,
                              hipStream_t stream) {
    const float* pred   = (const float*)d_in[0];
    const float* target = (const float*)d_in[1];
    const int n = in_sizes[0];                 // 16384

    // Workspace layout: [0,N) p_sorted (float) | [N,2N) K_sorted (int) | [2N,3N) tie_ctr (uint)
    float*        p_sorted = (float*)d_ws;
    int*          K_sorted = (int*)((char*)d_ws + (size_t)n * 4);
    unsigned int* tie_ctr  = (unsigned int*)((char*)d_ws + (size_t)n * 8);

    float* out = (float*)d_out;
    hipMemsetAsync(out, 0, sizeof(float) * (size_t)out_size, stream);
    hipMemsetAsync(tie_ctr, 0, (size_t)n * 4, stream);

    rank_scatter<<<n / R1, T, 0, stream>>>(pred, target, p_sorted, K_sorted, tie_ctr, n);
    hinge_sorted<<<n / R2, T, 0, stream>>>(p_sorted, K_sorted, out, n, 1.0f / (float)n);
}

// Round 5
// 92.471 us; speedup vs baseline: 1.2117x; 1.2117x over previous
//
#include <hip/hip_runtime.h>

// RankingLoss via target-rank counting sort:
//   loss = (1/N) * sum_i [ K_i>0 ? (sum_{j: t[j]<t[i]} max(0, m - p[i] + p[j])) / K_i : 0 ]
// Pass 1 (rank_scatter): strict rank K_i = #{t_j < t_i} via PER-LANE VALU
//   counting (2 VALU/pair, no ballot->SALU traffic); scatter pred into
//   target-sorted slots, ties resolved by atomic counter (set-invariant:
//   pass 2 only sums over the prefix [0, K_i), which is exactly {t_j < t_i}
//   regardless of tie order — tied elements land at slots >= K_i).
// Pass 2 (hinge_sorted): compare-free prefix hinge, 3 VALU/pair over N^2/2
//   pairs; per-block partials to ws (no atomics, no d_out memset).
// Pass 3 (final_reduce): 2048 partials -> d_out[0] with a plain store.

constexpr float MARGIN = 0.1f;
constexpr int T   = 256;   // threads per block
constexpr int R1  = 16;    // rows per block, pass 1
constexpr int R2  = 8;     // slots per block, pass 2

__global__ __launch_bounds__(T) void rank_scatter(const float* __restrict__ pred,
                                                  const float* __restrict__ target,
                                                  float* __restrict__ p_sorted,
                                                  int* __restrict__ K_sorted,
                                                  unsigned int* __restrict__ tie_ctr,
                                                  int n) {
    const int base = blockIdx.x * R1;

    float ti[R1];
    #pragma unroll
    for (int r = 0; r < R1; ++r) ti[r] = target[base + r];

    unsigned int cnt[R1];   // per-lane partial counts (VGPRs)
    #pragma unroll
    for (int r = 0; r < R1; ++r) cnt[r] = 0u;

    const float4* __restrict__ t4 = (const float4*)target;
    const int n4 = n >> 2;   // 4096, exact multiple of T: no partial waves

    for (int j = (int)threadIdx.x; j < n4; j += T) {
        const float4 tj = t4[j];
        #pragma unroll
        for (int r = 0; r < R1; ++r) {
            const float tir = ti[r];
            cnt[r] += (tj.x < tir) ? 1u : 0u;
            cnt[r] += (tj.y < tir) ? 1u : 0u;
            cnt[r] += (tj.z < tir) ? 1u : 0u;
            cnt[r] += (tj.w < tir) ? 1u : 0u;
        }
    }

    // Reduce per-lane counts: wave shuffle, then cross-wave via LDS.
    __shared__ unsigned int lc[T / 64][R1];
    const int lane = threadIdx.x & 63;
    const int wv   = threadIdx.x >> 6;

    #pragma unroll
    for (int r = 0; r < R1; ++r) {
        unsigned int c = cnt[r];
        #pragma unroll
        for (int off = 32; off > 0; off >>= 1) c += __shfl_down(c, off, 64);
        if (lane == 0) lc[wv][r] = c;
    }
    __syncthreads();

    if ((int)threadIdx.x < R1) {
        const int r = threadIdx.x;
        const unsigned int strict = lc[0][r] + lc[1][r] + lc[2][r] + lc[3][r];
        // Unique slot within the tie group (internal order irrelevant).
        const int slot = (int)strict + (int)atomicAdd(&tie_ctr[strict], 1u);
        p_sorted[slot] = pred[base + r];
        K_sorted[slot] = (int)strict;
    }
}

__global__ __launch_bounds__(T) void hinge_sorted(const float* __restrict__ p_sorted,
                                                  const int* __restrict__ K_sorted,
                                                  float* __restrict__ partials,
                                                  int n) {
    const int base = blockIdx.x * R2;

    float c[R2];
    int   K[R2];   // monotone non-decreasing in slot
    #pragma unroll
    for (int r = 0; r < R2; ++r) {
        K[r] = K_sorted[base + r];
        c[r] = MARGIN - p_sorted[base + r];
    }
    const int Kmin = K[0];
    const int Kmax = K[R2 - 1];

    float sum[R2];
    #pragma unroll
    for (int r = 0; r < R2; ++r) sum[r] = 0.f;

    // Main loop: compare-free over the common prefix [0, 4*(Kmin/4)).
    const float4* __restrict__ p4 = (const float4*)p_sorted;
    const int n4m = Kmin >> 2;
    for (int j = (int)threadIdx.x; j < n4m; j += T) {
        const float4 p = p4[j];
        #pragma unroll
        for (int r = 0; r < R2; ++r) {
            const float cr = c[r];
            sum[r] += fmaxf(0.f, cr + p.x);
            sum[r] += fmaxf(0.f, cr + p.y);
            sum[r] += fmaxf(0.f, cr + p.z);
            sum[r] += fmaxf(0.f, cr + p.w);
        }
    }

    // Predicated tail: j in [4*(Kmin/4), Kmax) — a handful of elements.
    for (int j = (n4m << 2) + (int)threadIdx.x; j < Kmax; j += T) {
        const float pj = p_sorted[j];
        #pragma unroll
        for (int r = 0; r < R2; ++r) {
            sum[r] += (j < K[r]) ? fmaxf(0.f, c[r] + pj) : 0.f;
        }
    }

    // Reduce sums across the block; one partial per block, no atomics.
    __shared__ float ls[T / 64][R2];
    __shared__ float row_val[R2];
    const int lane = threadIdx.x & 63;
    const int wv   = threadIdx.x >> 6;

    #pragma unroll
    for (int r = 0; r < R2; ++r) {
        float s = sum[r];
        #pragma unroll
        for (int off = 32; off > 0; off >>= 1) s += __shfl_down(s, off, 64);
        if (lane == 0) ls[wv][r] = s;
    }
    __syncthreads();

    if ((int)threadIdx.x < R2) {
        const int r = threadIdx.x;
        const float s = ls[0][r] + ls[1][r] + ls[2][r] + ls[3][r];
        row_val[r] = (K[r] > 0) ? (s / (float)K[r]) : 0.f;
    }
    __syncthreads();

    if (threadIdx.x == 0) {
        float local = 0.f;
        #pragma unroll
        for (int r = 0; r < R2; ++r) local += row_val[r];
        partials[blockIdx.x] = local;
    }
}

__global__ __launch_bounds__(T) void final_reduce(const float* __restrict__ partials,
                                                  float* __restrict__ out,
                                                  int nblk, float inv_n) {
    const float4* __restrict__ pr4 = (const float4*)partials;
    const int n4 = nblk >> 2;     // 512
    float s = 0.f;
    for (int j = (int)threadIdx.x; j < n4; j += T) {
        const float4 v = pr4[j];
        s += v.x + v.y + v.z + v.w;
    }
    #pragma unroll
    for (int off = 32; off > 0; off >>= 1) s += __shfl_down(s, off, 64);

    __shared__ float sd[T / 64];
    const int lane = threadIdx.x & 63;
    const int wv   = threadIdx.x >> 6;
    if (lane == 0) sd[wv] = s;
    __syncthreads();
    if (threadIdx.x == 0) {
        out[0] = (sd[0] + sd[1] + sd[2] + sd[3]) * inv_n;   // plain store: no memset of d_out needed
    }
}

extern "C" void kernel_launch(void* const* d_in, const int* in_sizes, int n_in,
                              void* d_out, int out_size, void* d_ws, size_t ws_size,
                              hipStream_t stream) {
    const float* pred   = (const float*)d_in[0];
    const float* target = (const float*)d_in[1];
    const int n = in_sizes[0];                 // 16384
    const int nblk2 = n / R2;                  // 2048

    // ws layout: p_sorted [0,N) | K_sorted [N,2N) | tie_ctr [2N,3N) | partials [3N, 3N+2048)
    float*        p_sorted = (float*)d_ws;
    int*          K_sorted = (int*)((char*)d_ws + (size_t)n * 4);
    unsigned int* tie_ctr  = (unsigned int*)((char*)d_ws + (size_t)n * 8);
    float*        partials = (float*)((char*)d_ws + (size_t)n * 12);

    hipMemsetAsync(tie_ctr, 0, (size_t)n * 4, stream);

    rank_scatter<<<n / R1, T, 0, stream>>>(pred, target, p_sorted, K_sorted, tie_ctr, n);
    hinge_sorted<<<nblk2, T, 0, stream>>>(p_sorted, K_sorted, partials, n);
    final_reduce<<<1, T, 0, stream>>>(partials, (float*)d_out, nblk2, 1.0f / (float)n);
}